// Round 8
// baseline (163.572 us; speedup 1.0000x reference)
//
#include <hip/hip_runtime.h>
#include <hip/hip_fp16.h>

#define B_SZ    16384
#define NNZ_PER 32
#define F_DIM   768
#define H_DIM   512
#define NRANGE  6            // f-ranges of 128 features
#define RF      128
#define PW      4            // positions per wave
#define WAVES   8            // 512-thread main blocks
#define PB      (WAVES * PW) // 32 positions per block

typedef unsigned int  uint32;
typedef unsigned long long uint64;
typedef unsigned char uchar;

// ws layout (bytes)
#define WT8_OFF  0u                              // [F][512] e5m2 = 393216
#define LIST_OFF 393216u                         // [B][6][64] u32 = 25165824
#define CNT_OFF  (393216u + 25165824u)           // [B][6] u32 = 393216

__device__ inline uchar f32_to_e5m2(float x) {
    __half h = __float2half_rn(x);
    unsigned short hb = *(unsigned short*)&h;
    unsigned short lsb = (hb >> 8) & 1;
    hb = (unsigned short)(hb + 0x7F + lsb);   // RNE into top 8 bits of fp16
    return (uchar)(hb >> 8);
}

// ---------------------------------------------------------------------------
// Fused prep.
// Blocks 0..383: transpose+quantize W_ft [H][F] fp32 -> Wt8 [F][512] e5m2
//   (linear layout == [range][128][512], ranges contiguous).
// Blocks 384..4479: bucketize (1 wave per position) into per-(pos,range)
//   64-slot lists: stm slots 0..31, nstm slots 32..63; counts packed; odd
//   counts padded with one zero entry (f=0, v=0 -> contributes nothing).
// ---------------------------------------------------------------------------
__global__ __launch_bounds__(256) void prep(
    const float* __restrict__ W,
    const int*   __restrict__ stm_idx,
    const int*   __restrict__ nstm_idx,
    const float* __restrict__ stm_val,
    const float* __restrict__ nstm_val,
    uchar*  __restrict__ Wt8,
    uint32* __restrict__ lists,
    uint32* __restrict__ counts)
{
    if (blockIdx.x < 384) {
        __shared__ float tile[32][33];
        const int bx = blockIdx.x % 24;
        const int by = blockIdx.x / 24;
        const int f0 = bx * 32, h0 = by * 32;
        const int tx = threadIdx.x & 31;
        const int ty = threadIdx.x >> 5;
#pragma unroll
        for (int i = 0; i < 32; i += 8)
            tile[ty + i][tx] = W[(h0 + ty + i) * F_DIM + f0 + tx];
        __syncthreads();
#pragma unroll
        for (int i = 0; i < 32; i += 8)
            Wt8[(size_t)(f0 + ty + i) * H_DIM + (h0 + tx)] =
                f32_to_e5m2(tile[tx][ty + i]);
    } else {
        const int wvp  = threadIdx.x >> 6;
        const int lane = threadIdx.x & 63;
        const int pos  = (blockIdx.x - 384) * 4 + wvp;
        const int NNZ  = B_SZ * NNZ_PER;

        int f; float v;
        if (lane < 32) { f = stm_idx [NNZ + pos * 32 + lane];        v = stm_val [pos * 32 + lane]; }
        else           { f = nstm_idx[NNZ + pos * 32 + (lane - 32)]; v = nstm_val[pos * 32 + (lane - 32)]; }
        const int range = f >> 7;
        __half hv = __float2half_rn(v);
        const uint32 entry = (uint32)(f & 127) |
                             ((uint32)(*(unsigned short*)&hv) << 16);
        const uint64 below = (1ull << lane) - 1;
        uint32* base = lists + (size_t)pos * (NRANGE * 64);

#pragma unroll
        for (int r = 0; r < NRANGE; ++r) {
            const uint64 m = __ballot(range == r);
            if (range == r) {
                const uint64 lower = m & below;
                const int slot = (lane < 32) ? __popc((uint32)lower)
                                             : 32 + __popc((uint32)(lower >> 32));
                base[r * 64 + slot] = entry;
            }
            if (lane == 0) {
                const int cs = __popc((uint32)m);
                const int cn = __popc((uint32)(m >> 32));
                if (cs & 1) base[r * 64 + cs] = 0;        // zero pad entry
                if (cn & 1) base[r * 64 + 32 + cn] = 0;
                counts[pos * NRANGE + r] = (uint32)cs | ((uint32)cn << 16);
            }
        }
    }
}

// ---------------------------------------------------------------------------
// Main: 512 blocks x 512 threads (8 waves), 2 blocks/CU (64 KB LDS).
// Per range: stage 128 f x 512 h fp8 -> LDS (contiguous), then each wave
// drains its 4 positions x 2 sides lists TWO entries at a time:
//   lanes 0-31 read row e1, lanes 32-63 row e2 (one contiguous-pair
//   ds_read_b128, 1 KB, conflict-free); offsets/values come from SGPRs
//   (readlane + SALU). Mirrored 16-h/lane fp16 accumulators per half-wave,
//   combined via shfl_xor(32) in the epilogue (lanes>=32 masked in the dot).
// ---------------------------------------------------------------------------
__global__ __launch_bounds__(512, 4) void nnue_main(
    const uchar*  __restrict__ Wt8,
    const uint32* __restrict__ lists,
    const uint32* __restrict__ counts,
    const float*  __restrict__ b_ft,
    const float*  __restrict__ W_out,
    const float*  __restrict__ b_out,
    float* __restrict__ out)
{
    __shared__ uchar Wl[RF * H_DIM];             // 65536 B
    const int tid   = threadIdx.x;
    const int wv    = tid >> 6;
    const int lane  = tid & 63;
    const int pbase = blockIdx.x * PB + wv * PW;
    const uint32 laneoff = (uint32)(lane & 31) << 4;
    const bool hi = (lane >= 32);

    const uint32 selA = 0x01040004u;             // [0,b0,0,b1] -> half2(h0,h1)
    const uint32 selB = 0x03040204u;             // [0,b2,0,b3] -> half2(h2,h3)

    __half2 z = __float2half2_rn(0.f);
    __half2 acc[PW][2][8];
#pragma unroll
    for (int p = 0; p < PW; ++p)
#pragma unroll
        for (int s = 0; s < 2; ++s)
#pragma unroll
            for (int k = 0; k < 8; ++k) acc[p][s][k] = z;

    for (int r = 0; r < NRANGE; ++r) {
        __syncthreads();
        {   // stage 64 KB contiguous
            const uchar* src = Wt8 + (size_t)r * (RF * H_DIM);
#pragma unroll
            for (int i = 0; i < 8; ++i) {
                const int o = i * 8192 + tid * 16;
                *(uint4*)(Wl + o) = *(const uint4*)(src + o);
            }
        }
        __syncthreads();

        uint32 el[PW], cw[PW];
#pragma unroll
        for (int p = 0; p < PW; ++p) {
            const int pr = (pbase + p) * NRANGE + r;
            el[p] = lists[(size_t)pr * 64 + lane];
            cw[p] = counts[pr];
        }

#pragma unroll
        for (int p = 0; p < PW; ++p) {
#pragma unroll
            for (int side = 0; side < 2; ++side) {
                const int c = side ? (int)(cw[p] >> 16) : (int)(cw[p] & 0xFFFFu);
                const int trips = (c + 1) >> 1;
                for (int j = 0; j < trips; ++j) {
                    const uint32 e1 = __builtin_amdgcn_readlane(el[p], side * 32 + 2 * j);
                    const uint32 e2 = __builtin_amdgcn_readlane(el[p], side * 32 + 2 * j + 1);
                    const uint32 off1 = (e1 & 127u) << 9;
                    const uint32 off2 = (e2 & 127u) << 9;
                    const uint32 off  = (hi ? off2 : off1) + laneoff;
                    const uint32 p1 = __builtin_amdgcn_perm(e1, e1, 0x03020302u);
                    const uint32 p2 = __builtin_amdgcn_perm(e2, e2, 0x03020302u);
                    const uint32 vvb = hi ? p2 : p1;
                    __half2 vv = *(const __half2*)&vvb;
                    uint4 w4 = *(const uint4*)(Wl + off);   // ds_read_b128
                    __half2* a = acc[p][side];
                    uint32 q;
                    q = __builtin_amdgcn_perm(0u, w4.x, selA); a[0] = __hfma2(*(__half2*)&q, vv, a[0]);
                    q = __builtin_amdgcn_perm(0u, w4.x, selB); a[1] = __hfma2(*(__half2*)&q, vv, a[1]);
                    q = __builtin_amdgcn_perm(0u, w4.y, selA); a[2] = __hfma2(*(__half2*)&q, vv, a[2]);
                    q = __builtin_amdgcn_perm(0u, w4.y, selB); a[3] = __hfma2(*(__half2*)&q, vv, a[3]);
                    q = __builtin_amdgcn_perm(0u, w4.z, selA); a[4] = __hfma2(*(__half2*)&q, vv, a[4]);
                    q = __builtin_amdgcn_perm(0u, w4.z, selB); a[5] = __hfma2(*(__half2*)&q, vv, a[5]);
                    q = __builtin_amdgcn_perm(0u, w4.w, selA); a[6] = __hfma2(*(__half2*)&q, vv, a[6]);
                    q = __builtin_amdgcn_perm(0u, w4.w, selB); a[7] = __hfma2(*(__half2*)&q, vv, a[7]);
                }
            }
        }
    }

    // Combine mirrored half-wave accumulators: lanes l and l+32 hold the same
    // h-range; after this both have full sums.
#pragma unroll
    for (int p = 0; p < PW; ++p)
#pragma unroll
        for (int s = 0; s < 2; ++s)
#pragma unroll
            for (int k = 0; k < 8; ++k) {
                int mi = *(int*)&acc[p][s][k];
                int oi = __shfl_xor(mi, 32, 64);
                acc[p][s][k] = __hadd2(acc[p][s][k], *(__half2*)&oi);
            }

    // Epilogue: lane (l = lane&31) owns h = l*16 + 2k, 2k+1.
    const int hbase = (lane & 31) * 16;
    float dotp[PW] = {0.f, 0.f, 0.f, 0.f};
#pragma unroll
    for (int k = 0; k < 8; ++k) {
        const float2 bi = *(const float2*)(b_ft  + hbase + 2 * k);
        const float2 ws = *(const float2*)(W_out + hbase + 2 * k);
        const float2 wn = *(const float2*)(W_out + H_DIM + hbase + 2 * k);
#pragma unroll
        for (int p = 0; p < PW; ++p) {
            const __half2 s2 = acc[p][0][k], n2 = acc[p][1][k];
            const float a0 = fminf(fmaxf(__low2float (s2) + bi.x, 0.f), 1.f);
            const float a1 = fminf(fmaxf(__high2float(s2) + bi.y, 0.f), 1.f);
            const float c0 = fminf(fmaxf(__low2float (n2) + bi.x, 0.f), 1.f);
            const float c1 = fminf(fmaxf(__high2float(n2) + bi.y, 0.f), 1.f);
            dotp[p] += a0 * ws.x + a1 * ws.y + c0 * wn.x + c1 * wn.y;
        }
    }

    const float bo = b_out[0];
#pragma unroll
    for (int p = 0; p < PW; ++p) {
        float d = hi ? 0.f : dotp[p];       // mask: each h counted once
#pragma unroll
        for (int off = 32; off > 0; off >>= 1)
            d += __shfl_xor(d, off, 64);
        if (lane == 0)
            out[pbase + p] = 1.f / (1.f + expf(-(d + bo)));
    }
}

extern "C" void kernel_launch(void* const* d_in, const int* in_sizes, int n_in,
                              void* d_out, int out_size, void* d_ws, size_t ws_size,
                              hipStream_t stream) {
    const int*   stm_idx  = (const int*)  d_in[0];
    const int*   nstm_idx = (const int*)  d_in[1];
    const float* stm_val  = (const float*)d_in[2];
    const float* nstm_val = (const float*)d_in[3];
    const float* W_ft     = (const float*)d_in[5];
    const float* b_ft     = (const float*)d_in[6];
    const float* W_out    = (const float*)d_in[7];
    const float* b_out    = (const float*)d_in[8];
    float*       out      = (float*)d_out;

    uchar*  Wt8    = (uchar*) ((char*)d_ws + WT8_OFF);
    uint32* lists  = (uint32*)((char*)d_ws + LIST_OFF);
    uint32* counts = (uint32*)((char*)d_ws + CNT_OFF);

    prep<<<384 + B_SZ / 4, 256, 0, stream>>>(
        W_ft, stm_idx, nstm_idx, stm_val, nstm_val, Wt8, lists, counts);

    nnue_main<<<B_SZ / PB, 512, 0, stream>>>(
        Wt8, lists, counts, b_ft, W_out, b_out, out);
}